// Round 8
// baseline (665.486 us; speedup 1.0000x reference)
//
#include <hip/hip_runtime.h>

#define T_STEPS 512
#define BATCH   256

typedef _Float16 f16;
typedef unsigned long long u64;
typedef __attribute__((ext_vector_type(8))) _Float16 f16x8;
typedef __attribute__((ext_vector_type(4))) _Float16 f16x4;
typedef __attribute__((ext_vector_type(4))) float    f32x4;

#define L2E 1.44269504088896340736f

__device__ __forceinline__ float rcp_f(float x)  { return __builtin_amdgcn_rcpf(x); }
__device__ __forceinline__ float exp2_f(float x) { return __builtin_amdgcn_exp2f(x); }

// tanh(x) = 1 - 2/(exp2(2*log2e*x)+1)
__device__ __forceinline__ float tanh_n(float x) {
    return fmaf(-2.0f, rcp_f(1.0f + exp2_f(2.0f * L2E * x)), 1.0f);
}

// Per-step barrier: LDS visibility only (global ops NOT drained).
__device__ __forceinline__ void barrier_lgkm() {
    asm volatile("s_waitcnt lgkmcnt(0)\n\ts_barrier" ::: "memory");
}
// Signal-point barrier: drain all VMEM so panels are globally visible.
__device__ __forceinline__ void barrier_drain() {
    asm volatile("s_waitcnt vmcnt(0) lgkmcnt(0)\n\ts_barrier" ::: "memory");
}

// Agent-scope relaxed atomics -> sc1 ops, coherent at L3 across XCDs.
__device__ __forceinline__ int  flag_load(const int* p) {
    return __hip_atomic_load(p, __ATOMIC_RELAXED, __HIP_MEMORY_SCOPE_AGENT);
}
__device__ __forceinline__ void flag_store(int* p, int v) {
    __hip_atomic_store(p, v, __ATOMIC_RELAXED, __HIP_MEMORY_SCOPE_AGENT);
}
__device__ __forceinline__ u64  panel_load(const u64* p) {
    return __hip_atomic_load(p, __ATOMIC_RELAXED, __HIP_MEMORY_SCOPE_AGENT);
}
__device__ __forceinline__ void panel_store(u64* p, u64 v) {
    __hip_atomic_store(p, v, __ATOMIC_RELAXED, __HIP_MEMORY_SCOPE_AGENT);
}

// One LSTM layer over one 16-batch group (NT = 4H threads).
// ROUND-8 OPERAND SWAP: weights are the MFMA A-operand, x/h panel the B-
// operand (same register contents as rounds 2-7, args swapped). C layout:
// row m = 4q+r = unit-in-tile, col = lane&15 = batch. Lane owns 4 contiguous
// units of one batch -> b64 h-write, register-direct panel/f32 stores.
// Weights/biases scaled by log2e (i,f,o) and 2*log2e (g); cell state kept in
// the 2*log2e domain; fused-rcp gates: 8 quarter-rate ops/cell.
// Pipeline: flag f = "x panels 0..f-1 globally visible"; producer publishes
// f = t at steps t%4==0 (after drain at end of step t-1); consumer at step
// tau prefetches x(tau+1) once flag >= tau+2.
template <int IN_DIM, int H, bool IN_F32, bool OUT_PANEL, bool OUT_TANH>
__device__ __forceinline__ void lstm_layer_dev(
    char* sm,
    const void* __restrict__ xv,       // IN_F32 ? f32 [T,B,IN] : f16 [T,B,IN]
    const int* in_flag,                // upstream flag (unused if IN_F32)
    int* out_flag,                     // our flag (unused if !OUT_PANEL)
    const float* __restrict__ w_ih, const float* __restrict__ w_hh,
    const float* __restrict__ b_ih, const float* __restrict__ b_hh,
    void* __restrict__ outv,           // OUT_PANEL ? f16 [T,B,H] : f32 [T,B,H]
    int group, int ltid)
{
    constexpr int KTX = IN_DIM / 32, KTH = H / 32, KT = KTX + KTH;
    constexpr int XP = IN_DIM + 8, HP = H + 8, NT = 4 * H;

    f16 (*xs)[16][XP] = (f16(*)[16][XP])sm;                       // [2][16][XP]
    f16 (*hs)[16][HP] = (f16(*)[16][HP])(sm + 2 * 16 * XP * 2);   // [2][16][HP]

    const int wave = ltid >> 6, lane = ltid & 63;
    const int col = lane & 15, q = lane >> 4;
    const int bblk = group * 16;
    const int u  = wave * 16 + col;    // weight-row index for frag loads
    const int uu = wave * 16 + 4 * q;  // first of this lane's 4 owned units

    // ---- one-time: weight A-fragments (log2e-scaled) -> registers ----
    // A-frag: lane supplies A[m=lane&15][k=q*8+j] = W[16*wave+col][k].
    f16x8 bw[4][KT];
#pragma unroll
    for (int g = 0; g < 4; ++g) {
        const float sc = (g == 2) ? 2.0f * L2E : L2E;
        const int row = g * H + u;
#pragma unroll
        for (int kt = 0; kt < KTX; ++kt) {
            const float* p = w_ih + (size_t)row * IN_DIM + kt * 32 + q * 8;
            f16x8 v;
#pragma unroll
            for (int j = 0; j < 8; ++j) v[j] = (f16)(p[j] * sc);
            bw[g][kt] = v;
        }
#pragma unroll
        for (int kt = 0; kt < KTH; ++kt) {
            const float* p = w_hh + (size_t)row * H + kt * 32 + q * 8;
            f16x8 v;
#pragma unroll
            for (int j = 0; j < 8; ++j) v[j] = (f16)(p[j] * sc);
            bw[g][KTX + kt] = v;
        }
    }
    // bias for the 4 owned units (rows uu..uu+3), per gate
    float bias[4][4];
#pragma unroll
    for (int g = 0; g < 4; ++g) {
        const float sc = (g == 2) ? 2.0f * L2E : L2E;
#pragma unroll
        for (int r = 0; r < 4; ++r)
            bias[g][r] = (b_ih[g * H + uu + r] + b_hh[g * H + uu + r]) * sc;
    }
    float cst[4] = {0.f, 0.f, 0.f, 0.f};   // cell state, 2*log2e domain

    // ---- input staging: 16B chunks (4 f32 or 8 f16) ----
    constexpr int ELD = IN_F32 ? 4 : 8;
    constexpr int EPR = IN_DIM / ELD;
    constexpr int NCH = 16 * EPR;
    constexpr int CPT = (NCH + NT - 1) / NT;
    constexpr long XADVB = (long)BATCH * IN_DIM * (IN_F32 ? 4 : 2);
    bool sv[CPT]; const char* sgp[CPT]; f16* slp[CPT];
    constexpr int LDSD = 16 * XP;          // f16 elems between xs buffers
#pragma unroll
    for (int k = 0; k < CPT; ++k) {
        const int cc = ltid + k * NT;
        sv[k] = (cc < NCH);
        const int r_ = (cc < NCH ? cc : 0) / EPR;
        const int o_ = (cc < NCH ? cc : 0) % EPR;
        sgp[k] = (const char*)xv + ((size_t)(bblk + r_) * IN_DIM + o_ * ELD) * (IN_F32 ? 4 : 2);
        slp[k] = &xs[0][r_][o_ * ELD];
    }

    // ---- output pointers (register-direct; batch=bblk+col, units uu..uu+3) ----
    u64*   ppg  = nullptr;
    float* optr = nullptr;
    if constexpr (OUT_PANEL)
        ppg = (u64*)((f16*)outv + ((size_t)bblk + col) * H + uu);
    else
        optr = (float*)outv + ((size_t)bblk + col) * H + uu;

    // ---- pre-loop: zero h(0); wait upstream; stage x(0) ----
    for (int i = ltid; i < 16 * HP; i += NT) hs[0][i / HP][i % HP] = (f16)0.f;
    int seen = 0;
    if constexpr (!IN_F32) {
        do { seen = flag_load(in_flag); } while (seen < 1);
    }
#pragma unroll
    for (int k = 0; k < CPT; ++k) {
        if (sv[k]) {
            if constexpr (IN_F32) {
                const f32x4 v = *reinterpret_cast<const f32x4*>(sgp[k]);
                f16x4 h4;
                h4[0] = (f16)v[0]; h4[1] = (f16)v[1]; h4[2] = (f16)v[2]; h4[3] = (f16)v[3];
                *reinterpret_cast<f16x4*>(slp[k]) = h4;
            } else {
                u64 a = panel_load((const u64*)sgp[k]);
                u64 b = panel_load((const u64*)sgp[k] + 1);
                u64 pk[2] = {a, b};
                *reinterpret_cast<f16x8*>(slp[k]) = *reinterpret_cast<const f16x8*>(pk);
            }
            sgp[k] += XADVB;
        }
    }
    barrier_drain();

    // ---- one step; pbv/dodrain/dopub are literal at each call site ----
    auto step = [&](int t, int pbv, bool dodrain, bool dopub) {
        if constexpr (OUT_PANEL) {
            if (dopub && t >= 4 && ltid == 0) flag_store(out_flag, t);
        }

        // prefetch x(t+1)
        f32x4 xr32[CPT]; u64 xr16[CPT][2];
        const bool pf = (t + 1 < T_STEPS);
        if (pf) {
            if constexpr (!IN_F32) {
                if (seen < t + 2) {
                    do { seen = flag_load(in_flag); } while (seen < t + 2);
                }
            }
#pragma unroll
            for (int k = 0; k < CPT; ++k) {
                if (sv[k]) {
                    if constexpr (IN_F32) {
                        xr32[k] = *reinterpret_cast<const f32x4*>(sgp[k]);
                    } else {
                        xr16[k][0] = panel_load((const u64*)sgp[k]);
                        xr16[k][1] = panel_load((const u64*)sgp[k] + 1);
                    }
                    sgp[k] += XADVB;
                }
            }
        }

        // B-fragments (x/h panel) from LDS: B[k=q*8+j][n=col]
        f16x8 a[KT];
#pragma unroll
        for (int kt = 0; kt < KTX; ++kt)
            a[kt] = *reinterpret_cast<const f16x8*>(&xs[pbv][col][kt * 32 + q * 8]);
#pragma unroll
        for (int kt = 0; kt < KTH; ++kt)
            a[KTX + kt] = *reinterpret_cast<const f16x8*>(&hs[pbv][col][kt * 32 + q * 8]);

        // MFMA: weights as A, panel as B -> C[m=unit][n=batch]
        f32x4 acc[4];
#pragma unroll
        for (int g = 0; g < 4; ++g)
            acc[g] = (f32x4){bias[g][0], bias[g][1], bias[g][2], bias[g][3]};
#pragma unroll
        for (int kt = 0; kt < KT; ++kt)
#pragma unroll
            for (int g = 0; g < 4; ++g)
                acc[g] = __builtin_amdgcn_mfma_f32_16x16x32_f16(bw[g][kt], a[kt], acc[g], 0, 0, 0);

        // gates, fused-rcp (8 quarter-rate ops/cell)
        float hf[4];
        f16x4 hv;
#pragma unroll
        for (int r = 0; r < 4; ++r) {
            const float zi = exp2_f(-acc[0][r]);
            const float zf = exp2_f(-acc[1][r]);
            const float zg = exp2_f(acc[2][r]);          // e^{2g}
            const float zo = exp2_f(-acc[3][r]);
            const float d1 = rcp_f((1.0f + zi) * (1.0f + zg));
            const float d2 = rcp_f(1.0f + zf);
            float cn = fmaf(cst[r], d2, (2.0f * L2E) * ((zg - 1.0f) * d1));
            cn = fminf(fmaxf(cn, -80.0f), 80.0f);        // exp2 overflow guard
            cst[r] = cn;
            const float zc = exp2_f(cn);                 // e^{2c}
            const float d3 = rcp_f((zc + 1.0f) * (1.0f + zo));
            const float h = (zc - 1.0f) * d3;            // so * tanh(c)
            hf[r] = h;
            hv[r] = (f16)h;
        }

        // recurrence write: 4 contiguous units, one b64
        *reinterpret_cast<f16x4*>(&hs[pbv ^ 1][col][uu]) = hv;

        // output for step t, direct from registers (off critical path)
        if constexpr (OUT_PANEL) {
            f16x4 pv = hv;
            if constexpr (OUT_TANH) {
#pragma unroll
                for (int r = 0; r < 4; ++r) pv[r] = (f16)tanh_n(hf[r]);
            }
            panel_store(ppg, __builtin_bit_cast(u64, pv));
            ppg += (size_t)BATCH * H / 4;
        } else {
            f32x4 ov = (f32x4){hf[0], hf[1], hf[2], hf[3]};
            *reinterpret_cast<f32x4*>(optr) = ov;
            optr += (size_t)BATCH * H;
        }

        // commit x(t+1) LAST (hides sc1 load latency under the step)
        if (pf) {
#pragma unroll
            for (int k = 0; k < CPT; ++k) {
                if (sv[k]) {
                    f16* dst = slp[k] + (pbv ^ 1) * LDSD;
                    if constexpr (IN_F32) {
                        f16x4 h4;
                        h4[0] = (f16)xr32[k][0]; h4[1] = (f16)xr32[k][1];
                        h4[2] = (f16)xr32[k][2]; h4[3] = (f16)xr32[k][3];
                        *reinterpret_cast<f16x4*>(dst) = h4;
                    } else {
                        *reinterpret_cast<f16x8*>(dst) =
                            *reinterpret_cast<const f16x8*>(xr16[k]);
                    }
                }
            }
        }

        // refresh 'seen' only on publish-cadence steps
        if constexpr (!IN_F32) {
            if (dopub && seen < t + 9) seen = flag_load(in_flag);
        }

        if (dodrain) barrier_drain(); else barrier_lgkm();
    };

    for (int tb = 0; tb < T_STEPS; tb += 4) {
        step(tb + 0, 0, false, true);
        step(tb + 1, 1, false, false);
        step(tb + 2, 0, false, false);
        step(tb + 3, 1, true,  false);
    }

    // ---- epilogue: all outputs already stored in-loop; drain + final flag ----
    barrier_drain();
    if constexpr (OUT_PANEL) {
        if (ltid == 0) flag_store(out_flag, T_STEPS + 4);
    }
}

__global__ __launch_bounds__(512, 1)
void lstm_fused(const float* __restrict__ X,
                const float* __restrict__ w1_ih, const float* __restrict__ w1_hh,
                const float* __restrict__ b1_ih, const float* __restrict__ b1_hh,
                const float* __restrict__ w2_ih, const float* __restrict__ w2_hh,
                const float* __restrict__ b2_ih, const float* __restrict__ b2_hh,
                const float* __restrict__ w3_ih, const float* __restrict__ w3_hh,
                const float* __restrict__ b3_ih, const float* __restrict__ b3_hh,
                const float* __restrict__ w4_ih, const float* __restrict__ w4_hh,
                const float* __restrict__ b4_ih, const float* __restrict__ b4_hh,
                f16* __restrict__ h1, f16* __restrict__ h2, f16* __restrict__ h3,
                int* __restrict__ flags, float* __restrict__ out)
{
    __shared__ __attribute__((aligned(16))) char smem[45056];
    const int b = blockIdx.x, tid = threadIdx.x;

    if (b < 16) {
        // L1: 64 -> 128, fp32 in, panel out, 1 group/block (512 thr)
        lstm_layer_dev<64, 128, true, true, false>(
            smem, X, nullptr, flags + 0 * 16 + b,
            w1_ih, w1_hh, b1_ih, b1_hh, h1, b, tid);
    } else if (b < 20) {
        // L2: 128 -> 32, 4 groups/block (128 thr each); bottleneck tanh on the
        // panel path only (recurrence h stays raw)
        const int gl = tid >> 7;
        const int g  = (b - 16) * 4 + gl;
        lstm_layer_dev<128, 32, false, true, true>(
            smem + gl * 11264, h1, flags + 0 * 16 + g, flags + 1 * 16 + g,
            w2_ih, w2_hh, b2_ih, b2_hh, h2, g, tid & 127);
    } else if (b < 36) {
        // L3: 32 -> 128; input panel h2 is already tanh'd
        const int g = b - 20;
        lstm_layer_dev<32, 128, false, true, false>(
            smem, h2, flags + 1 * 16 + g, flags + 2 * 16 + g,
            w3_ih, w3_hh, b3_ih, b3_hh, h3, g, tid);
    } else {
        // L4: 128 -> 64, 2 groups/block (256 thr each), fp32 final out
        const int gl = tid >> 8;
        const int g  = (b - 36) * 2 + gl;
        lstm_layer_dev<128, 64, false, false, false>(
            smem + gl * 13312, h3, flags + 2 * 16 + g, nullptr,
            w4_ih, w4_hh, b4_ih, b4_hh, out, g, tid & 255);
    }
}

extern "C" void kernel_launch(void* const* d_in, const int* in_sizes, int n_in,
                              void* d_out, int out_size, void* d_ws, size_t ws_size,
                              hipStream_t stream) {
    const float* X     = (const float*)d_in[0];
    const float* w1_ih = (const float*)d_in[1];
    const float* w1_hh = (const float*)d_in[2];
    const float* b1_ih = (const float*)d_in[3];
    const float* b1_hh = (const float*)d_in[4];
    const float* w2_ih = (const float*)d_in[5];
    const float* w2_hh = (const float*)d_in[6];
    const float* b2_ih = (const float*)d_in[7];
    const float* b2_hh = (const float*)d_in[8];
    const float* w3_ih = (const float*)d_in[9];
    const float* w3_hh = (const float*)d_in[10];
    const float* b3_ih = (const float*)d_in[11];
    const float* b3_hh = (const float*)d_in[12];
    const float* w4_ih = (const float*)d_in[13];
    const float* w4_hh = (const float*)d_in[14];
    const float* b4_ih = (const float*)d_in[15];
    const float* b4_hh = (const float*)d_in[16];

    float* out = (float*)d_out;

    // ws: flags[48] ints (poison 0xAAAAAAAA < 0 => "not ready"), then f16
    // panels h1 [T,B,128], h2 [T,B,32], h3 [T,B,128]
    int* flags = (int*)d_ws;
    f16* h1 = (f16*)((char*)d_ws + 256);
    f16* h2 = h1 + (size_t)T_STEPS * BATCH * 128;
    f16* h3 = h2 + (size_t)T_STEPS * BATCH * 32;

    lstm_fused<<<44, 512, 0, stream>>>(X,
        w1_ih, w1_hh, b1_ih, b1_hh, w2_ih, w2_hh, b2_ih, b2_hh,
        w3_ih, w3_hh, b3_ih, b3_hh, w4_ih, w4_hh, b4_ih, b4_hh,
        h1, h2, h3, flags, out);
}